// Round 15
// baseline (370.751 us; speedup 1.0000x reference)
//
#include <hip/hip_runtime.h>
#include <hip/hip_fp16.h>

// Problem constants (fixed by the reference file)
#define M_DIM 16384   // B*S = 4*4096
#define N_DIM 4096    // DOUT
#define K_DIM 4096    // DIN

typedef __attribute__((ext_vector_type(16))) float f32x16;
typedef __attribute__((ext_vector_type(4)))  int   i32x4;
typedef __attribute__((ext_vector_type(8)))  int   i32x8;

union frag_u { i32x8 v; i32x4 h[2]; };

// ---------------------------------------------------------------------------
// Direct-store fused quantizer (x -> e5m2, w -> e4m3fn), no LDS bounce.
// Emits the r12-verified 256-row fragment-order tiled layout, bit-identical:
//   out = [nrow/256][K/64] tiles of 16384 B; tile byte
//   p = sb*2048 + half*1024 + hi*512 + (r&31)*16 + b   <->
//   row = 256*bt + sb*32 + (r&31), k = 64*kt + hi*32 + half*16 + b.
// Work split: block = 4 consecutive rows; wave q = k-quarter [q*1024,
// q*1024+1024); lane l = 16 k's at k0 = q*1024 + l*16, all 4 rows.
//   Writes: the 4 rows' 16 B slots are CONTIGUOUS (r31*16, r31 % 4 == 0) ->
//   each thread stores 64 B contiguous (4 uint4s), sector fully filled by
//   its own stores (clean L2 write-combining, no RMW at HBM).
//   Reads: per inst 16 B @ 64 B stride; the 4 insts of a row tile the span
//   completely and hit L1 between insts -> no HBM over-fetch.
// Grid: 4096 x-blocks (16384 rows) + 1024 w-blocks (4096 rows).
// ---------------------------------------------------------------------------
__global__ __launch_bounds__(256) void quant_fused_kernel(
    const float* __restrict__ x, const float* __restrict__ w,
    uint4* __restrict__ xq, uint4* __restrict__ wq)
{
  const int b = blockIdx.x;               // 0..5119
  const float* in;
  uint4* out;
  int R;
  bool e4m3;
  if (b < 4096) { in = x; out = xq; R = b * 4;            e4m3 = false; }
  else          { in = w; out = wq; R = (b - 4096) * 4;   e4m3 = true;  }

  const int t  = threadIdx.x;
  const int q  = t >> 6;                  // k-quarter 0..3
  const int l  = t & 63;
  const int k0 = q * 1024 + l * 16;       // first of this thread's 16 k's
  const int kt = k0 >> 6;                 // K-tile 0..63
  const int c  = (k0 >> 4) & 3;           // {half,hi} chunk selector
  const int bt = R >> 8;                  // 256-row block
  const int sb = (R >> 5) & 7;            // 32-row sub-block
  const int r31 = R & 31;                 // multiple of 4

  uint4* op = out + (size_t)(bt * 64 + kt) * 1024
            + ((sb * 2048 + (c & 1) * 1024 + (c >> 1) * 512 + r31 * 16) >> 4);
  const float* ip = in + (size_t)R * K_DIM + k0;

  #pragma unroll
  for (int j = 0; j < 4; ++j) {           // 4 consecutive rows
    const float4* p = reinterpret_cast<const float4*>(ip + (size_t)j * K_DIM);
    float4 v0 = p[0], v1 = p[1], v2 = p[2], v3 = p[3];
    int w0 = 0, w1 = 0, w2 = 0, w3 = 0;
    if (e4m3) {
      w0 = __builtin_amdgcn_cvt_pk_fp8_f32(v0.x, v0.y, w0, false);
      w0 = __builtin_amdgcn_cvt_pk_fp8_f32(v0.z, v0.w, w0, true);
      w1 = __builtin_amdgcn_cvt_pk_fp8_f32(v1.x, v1.y, w1, false);
      w1 = __builtin_amdgcn_cvt_pk_fp8_f32(v1.z, v1.w, w1, true);
      w2 = __builtin_amdgcn_cvt_pk_fp8_f32(v2.x, v2.y, w2, false);
      w2 = __builtin_amdgcn_cvt_pk_fp8_f32(v2.z, v2.w, w2, true);
      w3 = __builtin_amdgcn_cvt_pk_fp8_f32(v3.x, v3.y, w3, false);
      w3 = __builtin_amdgcn_cvt_pk_fp8_f32(v3.z, v3.w, w3, true);
    } else {
      w0 = __builtin_amdgcn_cvt_pk_bf8_f32(v0.x, v0.y, w0, false);
      w0 = __builtin_amdgcn_cvt_pk_bf8_f32(v0.z, v0.w, w0, true);
      w1 = __builtin_amdgcn_cvt_pk_bf8_f32(v1.x, v1.y, w1, false);
      w1 = __builtin_amdgcn_cvt_pk_bf8_f32(v1.z, v1.w, w1, true);
      w2 = __builtin_amdgcn_cvt_pk_bf8_f32(v2.x, v2.y, w2, false);
      w2 = __builtin_amdgcn_cvt_pk_bf8_f32(v2.z, v2.w, w2, true);
      w3 = __builtin_amdgcn_cvt_pk_bf8_f32(v3.x, v3.y, w3, false);
      w3 = __builtin_amdgcn_cvt_pk_bf8_f32(v3.z, v3.w, w3, true);
    }
    op[j] = make_uint4((unsigned)w0, (unsigned)w1, (unsigned)w2, (unsigned)w3);
  }
}

// ---------------------------------------------------------------------------
// MX-fp8 GEMM — r12 best (FROZEN): 256x256 block tile, BK=64, 8 waves
// (2M x 4N), per-wave 128x64 = acc[4][2] f32x16, 2 waves/SIMD, wave-group
// phase stagger, 4 LDS bufs x 32 KiB, r11 ledger (stage 3 ahead / read 1
// ahead / confirm 2 ahead; vmcnt(4)/tile, never 0; 1 barrier/tile).
// ---------------------------------------------------------------------------
__global__ __launch_bounds__(512, 2) void gemm_fp8_kernel(
    const unsigned char* __restrict__ Aq,   // tiled [64][64][16384] e5m2
    const unsigned char* __restrict__ Wq,   // tiled [16][64][16384] e4m3
    const float* __restrict__ bias,         // [N] fp16-exact values in f32
    float* __restrict__ C)                  // [M,N] f32 (fp16-rounded values)
{
  __shared__ __align__(16) unsigned char lds[131072];  // 4 x {A 16K, B 16K}

  const int tid  = threadIdx.x;
  const int lane = tid & 63;
  const int wave = tid >> 6;                // 0..7
  const int wr   = wave >> 2;               // 0..1 -> 128 rows; stagger group
  const int wc   = wave & 3;                // 0..3 -> 64 cols

  const int bid = blockIdx.x;
  const int swz = (bid & 7) * 128 + (bid >> 3);
  const int bmi = swz >> 4;                 // 0..63
  const int bni = swz & 15;                 // 0..15

  const unsigned char* tA = Aq + (size_t)bmi * (64 * 16384);
  const unsigned char* tB = Wq + (size_t)bni * (64 * 16384);

  const size_t t16 = (size_t)tid * 16;
  const int    w1k = wave * 1024;

#define STAGE(gb, lo_)                                                      \
  __builtin_amdgcn_global_load_lds(                                        \
      (const __attribute__((address_space(1))) void*)((gb) + t16),          \
      (__attribute__((address_space(3))) void*)(lds + (lo_) + w1k), 16, 0, 0)

#define STAGE_TILE(tp, base)                                                \
  STAGE(tA + (tp), (base));          STAGE(tA + (tp) + 8192, (base) + 8192); \
  STAGE(tB + (tp), (base) + 16384);  STAGE(tB + (tp) + 8192, (base) + 24576)

#define RD8(dst, off)                                                       \
  { const unsigned char* _p = lds + (off) + lane * 16;                      \
    (dst).h[0] = *reinterpret_cast<const i32x4*>(_p);                       \
    (dst).h[1] = *reinterpret_cast<const i32x4*>(_p + 1024); }

#define MFMA(d, a, b)                                                       \
  d = __builtin_amdgcn_mfma_scale_f32_32x32x64_f8f6f4(                      \
      a, b, d, 1 /*A=e5m2*/, 0 /*B=e4m3*/, 0, 0x7F7F7F7F, 0, 0x7F7F7F7F)

#define SBAR __builtin_amdgcn_sched_barrier(0)
#define P1   __builtin_amdgcn_s_setprio(1)
#define P0   __builtin_amdgcn_s_setprio(0)

  const int aoff = wr * 8192;
  const int boff = 16384 + wc * 4096;

  f32x16 acc[4][2] = {};
  frag_u Ea0, Ea1, Ea2, Ea3, Eb0, Eb1;
  frag_u Oa0, Oa1, Oa2, Oa3, Ob0, Ob1;

#define RDTILE(s, buf)                                                      \
  RD8(s##a0, (buf) + aoff);        RD8(s##a1, (buf) + aoff + 2048);         \
  RD8(s##a2, (buf) + aoff + 4096); RD8(s##a3, (buf) + aoff + 6144);         \
  RD8(s##b0, (buf) + boff);        RD8(s##b1, (buf) + boff + 2048)

#define MFMAC(s)                                                            \
  P1;                                                                       \
  MFMA(acc[0][0], s##a0.v, s##b0.v);  MFMA(acc[0][1], s##a0.v, s##b1.v);    \
  MFMA(acc[1][0], s##a1.v, s##b0.v);  MFMA(acc[1][1], s##a1.v, s##b1.v);    \
  MFMA(acc[2][0], s##a2.v, s##b0.v);  MFMA(acc[2][1], s##a2.v, s##b1.v);    \
  MFMA(acc[3][0], s##a3.v, s##b0.v);  MFMA(acc[3][1], s##a3.v, s##b1.v);    \
  P0

#define TAIL(stbuf, tp)                                                     \
  SBAR;                                                                     \
  STAGE_TILE(tp, stbuf);                                                    \
  SBAR;                                                                     \
  asm volatile("s_waitcnt vmcnt(4)" ::: "memory");                          \
  SBAR;                                                                     \
  __builtin_amdgcn_s_barrier()

#define TILE_RF(rdset, mfset, rdbuf, stbuf, tp)                             \
  SBAR; RDTILE(rdset, rdbuf); SBAR; MFMAC(mfset); TAIL(stbuf, tp)
#define TILE_FR(rdset, mfset, rdbuf, stbuf, tp)                             \
  SBAR; MFMAC(mfset); SBAR; RDTILE(rdset, rdbuf); TAIL(stbuf, tp)

  // ---- Prologue: stage tiles 0,1,2 -> bufs 0,1,2; read tile-0 frags.
  STAGE_TILE(0, 0);
  STAGE_TILE(16384, 32768);
  STAGE_TILE(32768, 65536);
  SBAR;
  asm volatile("s_waitcnt vmcnt(4)" ::: "memory");   // tiles 0,1 landed
  SBAR;
  __builtin_amdgcn_s_barrier();
  SBAR;
  RDTILE(E, 0);
  SBAR;

  if (wr == 0) {
    for (int it = 0; it < 16; ++it) {
      const int t = it << 2;
      const size_t tp3 = (size_t)((t + 3) & 63) * 16384;
      const size_t tp4 = (size_t)((t + 4) & 63) * 16384;
      const size_t tp5 = (size_t)((t + 5) & 63) * 16384;
      const size_t tp6 = (size_t)((t + 6) & 63) * 16384;
      TILE_RF(O, E, 32768, 98304, tp3);
      TILE_RF(E, O, 65536, 0,     tp4);
      TILE_RF(O, E, 98304, 32768, tp5);
      TILE_RF(E, O, 0,     65536, tp6);
    }
  } else {
    for (int it = 0; it < 16; ++it) {
      const int t = it << 2;
      const size_t tp3 = (size_t)((t + 3) & 63) * 16384;
      const size_t tp4 = (size_t)((t + 4) & 63) * 16384;
      const size_t tp5 = (size_t)((t + 5) & 63) * 16384;
      const size_t tp6 = (size_t)((t + 6) & 63) * 16384;
      TILE_FR(O, E, 32768, 98304, tp3);
      TILE_FR(E, O, 65536, 0,     tp4);
      TILE_FR(O, E, 98304, 32768, tp5);
      TILE_FR(E, O, 0,     65536, tp6);
    }
  }
#undef STAGE
#undef STAGE_TILE
#undef RD8
#undef RDTILE
#undef MFMA
#undef MFMAC
#undef TAIL
#undef TILE_RF
#undef TILE_FR
#undef SBAR
#undef P1
#undef P0

  // Epilogue: +bias, round through fp16 (matches reference), store f32.
  // 32x32 C/D layout (verified r3-r14): col = lane&31,
  // row = (r&3) + 8*(r>>2) + 4*(lane>>5).
  #pragma unroll
  for (int n = 0; n < 2; ++n) {
    const int col = bni * 256 + wc * 64 + n * 32 + (lane & 31);
    const float bv = bias[col];
    #pragma unroll
    for (int m = 0; m < 4; ++m) {
      const int rbase = bmi * 256 + wr * 128 + m * 32 + ((lane >> 5) << 2);
      #pragma unroll
      for (int r = 0; r < 16; ++r) {
        const int row = rbase + (r & 3) + 8 * (r >> 2);
        C[(size_t)row * N_DIM + col] =
            __half2float(__float2half_rn(acc[m][n][r] + bv));
      }
    }
  }
}

// ---------------------------------------------------------------------------
extern "C" void kernel_launch(void* const* d_in, const int* in_sizes, int n_in,
                              void* d_out, int out_size, void* d_ws, size_t ws_size,
                              hipStream_t stream) {
  const float* x  = (const float*)d_in[0];   // [B,S,DIN] fp16-exact values in f32
  const float* w  = (const float*)d_in[1];   // [DOUT,DIN]
  const float* bs = (const float*)d_in[2];   // [DOUT]
  float* out = (float*)d_out;

  // Workspace: xq = 64 MiB e5m2 (tiled), wq = 16 MiB e4m3 (tiled)
  unsigned char* xq = (unsigned char*)d_ws;
  unsigned char* wq = (unsigned char*)d_ws + (size_t)M_DIM * K_DIM;

  // Direct-store fused quant: 4096 x-blocks + 1024 w-blocks, 4 rows each.
  quant_fused_kernel<<<5120, 256, 0, stream>>>(x, w, (uint4*)xq, (uint4*)wq);

  gemm_fp8_kernel<<<1024, 512, 0, stream>>>(xq, wq, bs, out);
}

// Round 16
// 341.856 us; speedup vs baseline: 1.0845x; 1.0845x over previous
//
#include <hip/hip_runtime.h>
#include <hip/hip_fp16.h>

// Problem constants (fixed by the reference file)
#define M_DIM 16384   // B*S = 4*4096
#define N_DIM 4096    // DOUT
#define K_DIM 4096    // DIN

typedef __attribute__((ext_vector_type(16))) float f32x16;
typedef __attribute__((ext_vector_type(4)))  int   i32x4;
typedef __attribute__((ext_vector_type(8)))  int   i32x8;

union frag_u { i32x8 v; i32x4 h[2]; };

// ---------------------------------------------------------------------------
// Fully-coalesced fused quantizer (x -> e5m2, w -> e4m3fn) via LDS bounce.
// (r14-measured best: ~93 us; r15's direct-store variant regressed to ~120 us
// from scattered 64 B stores.) Emits the r12-verified 256-row fragment-order
// tiled layout, bit-identical:
//   out = [nrow/256][K/64] tiles of 16384 B; tile byte
//   p = sb*2048 + half*1024 + hi*512 + (r&31)*16 + b   <->
//   row = 256*bt + sb*32 + (r&31), k = 64*kt + hi*32 + half*16 + b.
// One block per tile. Phase 1: task (row r, 16-k chunk c): 4 consecutive
// lanes cover one row's 64 contiguous B; convert 16 floats -> 16 fp8 B ->
// ONE ds_write_b128 at the XOR-swizzled layout position (p ^= ((p>>9)&3)<<4,
// involutive, kills the (hi,half) 4-way bank collision). Phase 2: 16 B/lane
// swizzled readback + fully-coalesced 4 KB/wave global store.
// Grid: 4096 x-tiles then 1024 w-tiles.
// ---------------------------------------------------------------------------
__global__ __launch_bounds__(256) void quant_fused_kernel(
    const float* __restrict__ x, const float* __restrict__ w,
    uint4* __restrict__ xq, uint4* __restrict__ wq)
{
  __shared__ __align__(16) unsigned char sts[16384];
  const int b = blockIdx.x;
  const float* in;
  uint4* out;
  int tile;
  bool e4m3;
  if (b < 4096) { in = x; out = xq; tile = b; e4m3 = false; }
  else          { in = w; out = wq; tile = b - 4096; e4m3 = true; }
  const int kt = tile & 63;       // K-tile 0..63
  const int bt = tile >> 6;       // 256-row block
  const int t  = threadIdx.x;

  #pragma unroll
  for (int iter = 0; iter < 4; ++iter) {
    const int r = iter * 64 + (t >> 2);     // row within tile 0..255
    const int c = t & 3;                    // 16-float k-chunk 0..3
    const float4* p = reinterpret_cast<const float4*>(
        in + (size_t)(bt * 256 + r) * K_DIM + kt * 64 + c * 16);
    float4 v0 = p[0], v1 = p[1], v2 = p[2], v3 = p[3];
    int w0 = 0, w1 = 0, w2 = 0, w3 = 0;
    if (e4m3) {
      w0 = __builtin_amdgcn_cvt_pk_fp8_f32(v0.x, v0.y, w0, false);
      w0 = __builtin_amdgcn_cvt_pk_fp8_f32(v0.z, v0.w, w0, true);
      w1 = __builtin_amdgcn_cvt_pk_fp8_f32(v1.x, v1.y, w1, false);
      w1 = __builtin_amdgcn_cvt_pk_fp8_f32(v1.z, v1.w, w1, true);
      w2 = __builtin_amdgcn_cvt_pk_fp8_f32(v2.x, v2.y, w2, false);
      w2 = __builtin_amdgcn_cvt_pk_fp8_f32(v2.z, v2.w, w2, true);
      w3 = __builtin_amdgcn_cvt_pk_fp8_f32(v3.x, v3.y, w3, false);
      w3 = __builtin_amdgcn_cvt_pk_fp8_f32(v3.z, v3.w, w3, true);
    } else {
      w0 = __builtin_amdgcn_cvt_pk_bf8_f32(v0.x, v0.y, w0, false);
      w0 = __builtin_amdgcn_cvt_pk_bf8_f32(v0.z, v0.w, w0, true);
      w1 = __builtin_amdgcn_cvt_pk_bf8_f32(v1.x, v1.y, w1, false);
      w1 = __builtin_amdgcn_cvt_pk_bf8_f32(v1.z, v1.w, w1, true);
      w2 = __builtin_amdgcn_cvt_pk_bf8_f32(v2.x, v2.y, w2, false);
      w2 = __builtin_amdgcn_cvt_pk_bf8_f32(v2.z, v2.w, w2, true);
      w3 = __builtin_amdgcn_cvt_pk_bf8_f32(v3.x, v3.y, w3, false);
      w3 = __builtin_amdgcn_cvt_pk_bf8_f32(v3.z, v3.w, w3, true);
    }
    // Layout position: sb=r>>5, l31=r&31, hi=c>>1, half=c&1; b = 0..15.
    int ppos = (r >> 5) * 2048 + (c & 1) * 1024 + (c >> 1) * 512 + (r & 31) * 16;
    ppos ^= ((ppos >> 9) & 3) << 4;         // bank swizzle (involutive)
    *reinterpret_cast<uint4*>(sts + ppos) = make_uint4(
        (unsigned)w0, (unsigned)w1, (unsigned)w2, (unsigned)w3);
  }
  __syncthreads();
  const size_t obase = (size_t)tile * 1024;   // uint4 index of tile start
  #pragma unroll
  for (int j = 0; j < 4; ++j) {
    const int q  = j * 4096 + t * 16;         // linear tile byte
    const int qs = q ^ (((q >> 9) & 3) << 4); // same involution
    out[obase + (q >> 4)] = *reinterpret_cast<const uint4*>(sts + qs);
  }
}

// ---------------------------------------------------------------------------
// MX-fp8 GEMM — r12 best (FROZEN): 256x256 block tile, BK=64, 8 waves
// (2M x 4N), per-wave 128x64 = acc[4][2] f32x16, 2 waves/SIMD, wave-group
// phase stagger, 4 LDS bufs x 32 KiB, r11 ledger (stage 3 ahead / read 1
// ahead / confirm 2 ahead; vmcnt(4)/tile, never 0; 1 barrier/tile).
// Plateau evidence: r8/r9/r10/r11/r12/r13 all land 245-360 us; this is the
// measured best (~248 us, MfmaUtil ~50%).
// ---------------------------------------------------------------------------
__global__ __launch_bounds__(512, 2) void gemm_fp8_kernel(
    const unsigned char* __restrict__ Aq,   // tiled [64][64][16384] e5m2
    const unsigned char* __restrict__ Wq,   // tiled [16][64][16384] e4m3
    const float* __restrict__ bias,         // [N] fp16-exact values in f32
    float* __restrict__ C)                  // [M,N] f32 (fp16-rounded values)
{
  __shared__ __align__(16) unsigned char lds[131072];  // 4 x {A 16K, B 16K}

  const int tid  = threadIdx.x;
  const int lane = tid & 63;
  const int wave = tid >> 6;                // 0..7
  const int wr   = wave >> 2;               // 0..1 -> 128 rows; stagger group
  const int wc   = wave & 3;                // 0..3 -> 64 cols

  const int bid = blockIdx.x;
  const int swz = (bid & 7) * 128 + (bid >> 3);
  const int bmi = swz >> 4;                 // 0..63
  const int bni = swz & 15;                 // 0..15

  const unsigned char* tA = Aq + (size_t)bmi * (64 * 16384);
  const unsigned char* tB = Wq + (size_t)bni * (64 * 16384);

  const size_t t16 = (size_t)tid * 16;
  const int    w1k = wave * 1024;

#define STAGE(gb, lo_)                                                      \
  __builtin_amdgcn_global_load_lds(                                        \
      (const __attribute__((address_space(1))) void*)((gb) + t16),          \
      (__attribute__((address_space(3))) void*)(lds + (lo_) + w1k), 16, 0, 0)

#define STAGE_TILE(tp, base)                                                \
  STAGE(tA + (tp), (base));          STAGE(tA + (tp) + 8192, (base) + 8192); \
  STAGE(tB + (tp), (base) + 16384);  STAGE(tB + (tp) + 8192, (base) + 24576)

#define RD8(dst, off)                                                       \
  { const unsigned char* _p = lds + (off) + lane * 16;                      \
    (dst).h[0] = *reinterpret_cast<const i32x4*>(_p);                       \
    (dst).h[1] = *reinterpret_cast<const i32x4*>(_p + 1024); }

#define MFMA(d, a, b)                                                       \
  d = __builtin_amdgcn_mfma_scale_f32_32x32x64_f8f6f4(                      \
      a, b, d, 1 /*A=e5m2*/, 0 /*B=e4m3*/, 0, 0x7F7F7F7F, 0, 0x7F7F7F7F)

#define SBAR __builtin_amdgcn_sched_barrier(0)
#define P1   __builtin_amdgcn_s_setprio(1)
#define P0   __builtin_amdgcn_s_setprio(0)

  const int aoff = wr * 8192;
  const int boff = 16384 + wc * 4096;

  f32x16 acc[4][2] = {};
  frag_u Ea0, Ea1, Ea2, Ea3, Eb0, Eb1;
  frag_u Oa0, Oa1, Oa2, Oa3, Ob0, Ob1;

#define RDTILE(s, buf)                                                      \
  RD8(s##a0, (buf) + aoff);        RD8(s##a1, (buf) + aoff + 2048);         \
  RD8(s##a2, (buf) + aoff + 4096); RD8(s##a3, (buf) + aoff + 6144);         \
  RD8(s##b0, (buf) + boff);        RD8(s##b1, (buf) + boff + 2048)

#define MFMAC(s)                                                            \
  P1;                                                                       \
  MFMA(acc[0][0], s##a0.v, s##b0.v);  MFMA(acc[0][1], s##a0.v, s##b1.v);    \
  MFMA(acc[1][0], s##a1.v, s##b0.v);  MFMA(acc[1][1], s##a1.v, s##b1.v);    \
  MFMA(acc[2][0], s##a2.v, s##b0.v);  MFMA(acc[2][1], s##a2.v, s##b1.v);    \
  MFMA(acc[3][0], s##a3.v, s##b0.v);  MFMA(acc[3][1], s##a3.v, s##b1.v);    \
  P0

#define TAIL(stbuf, tp)                                                     \
  SBAR;                                                                     \
  STAGE_TILE(tp, stbuf);                                                    \
  SBAR;                                                                     \
  asm volatile("s_waitcnt vmcnt(4)" ::: "memory");                          \
  SBAR;                                                                     \
  __builtin_amdgcn_s_barrier()

#define TILE_RF(rdset, mfset, rdbuf, stbuf, tp)                             \
  SBAR; RDTILE(rdset, rdbuf); SBAR; MFMAC(mfset); TAIL(stbuf, tp)
#define TILE_FR(rdset, mfset, rdbuf, stbuf, tp)                             \
  SBAR; MFMAC(mfset); SBAR; RDTILE(rdset, rdbuf); TAIL(stbuf, tp)

  // ---- Prologue: stage tiles 0,1,2 -> bufs 0,1,2; read tile-0 frags.
  STAGE_TILE(0, 0);
  STAGE_TILE(16384, 32768);
  STAGE_TILE(32768, 65536);
  SBAR;
  asm volatile("s_waitcnt vmcnt(4)" ::: "memory");   // tiles 0,1 landed
  SBAR;
  __builtin_amdgcn_s_barrier();
  SBAR;
  RDTILE(E, 0);
  SBAR;

  if (wr == 0) {
    for (int it = 0; it < 16; ++it) {
      const int t = it << 2;
      const size_t tp3 = (size_t)((t + 3) & 63) * 16384;
      const size_t tp4 = (size_t)((t + 4) & 63) * 16384;
      const size_t tp5 = (size_t)((t + 5) & 63) * 16384;
      const size_t tp6 = (size_t)((t + 6) & 63) * 16384;
      TILE_RF(O, E, 32768, 98304, tp3);
      TILE_RF(E, O, 65536, 0,     tp4);
      TILE_RF(O, E, 98304, 32768, tp5);
      TILE_RF(E, O, 0,     65536, tp6);
    }
  } else {
    for (int it = 0; it < 16; ++it) {
      const int t = it << 2;
      const size_t tp3 = (size_t)((t + 3) & 63) * 16384;
      const size_t tp4 = (size_t)((t + 4) & 63) * 16384;
      const size_t tp5 = (size_t)((t + 5) & 63) * 16384;
      const size_t tp6 = (size_t)((t + 6) & 63) * 16384;
      TILE_FR(O, E, 32768, 98304, tp3);
      TILE_FR(E, O, 65536, 0,     tp4);
      TILE_FR(O, E, 98304, 32768, tp5);
      TILE_FR(E, O, 0,     65536, tp6);
    }
  }
#undef STAGE
#undef STAGE_TILE
#undef RD8
#undef RDTILE
#undef MFMA
#undef MFMAC
#undef TAIL
#undef TILE_RF
#undef TILE_FR
#undef SBAR
#undef P1
#undef P0

  // Epilogue: +bias, round through fp16 (matches reference), store f32.
  // 32x32 C/D layout (verified r3-r15): col = lane&31,
  // row = (r&3) + 8*(r>>2) + 4*(lane>>5).
  #pragma unroll
  for (int n = 0; n < 2; ++n) {
    const int col = bni * 256 + wc * 64 + n * 32 + (lane & 31);
    const float bv = bias[col];
    #pragma unroll
    for (int m = 0; m < 4; ++m) {
      const int rbase = bmi * 256 + wr * 128 + m * 32 + ((lane >> 5) << 2);
      #pragma unroll
      for (int r = 0; r < 16; ++r) {
        const int row = rbase + (r & 3) + 8 * (r >> 2);
        C[(size_t)row * N_DIM + col] =
            __half2float(__float2half_rn(acc[m][n][r] + bv));
      }
    }
  }
}

// ---------------------------------------------------------------------------
extern "C" void kernel_launch(void* const* d_in, const int* in_sizes, int n_in,
                              void* d_out, int out_size, void* d_ws, size_t ws_size,
                              hipStream_t stream) {
  const float* x  = (const float*)d_in[0];   // [B,S,DIN] fp16-exact values in f32
  const float* w  = (const float*)d_in[1];   // [DOUT,DIN]
  const float* bs = (const float*)d_in[2];   // [DOUT]
  float* out = (float*)d_out;

  // Workspace: xq = 64 MiB e5m2 (tiled), wq = 16 MiB e4m3 (tiled)
  unsigned char* xq = (unsigned char*)d_ws;
  unsigned char* wq = (unsigned char*)d_ws + (size_t)M_DIM * K_DIM;

  // Fused coalesced quant: 4096 x-tiles + 1024 w-tiles.
  quant_fused_kernel<<<5120, 256, 0, stream>>>(x, w, (uint4*)xq, (uint4*)wq);

  gemm_fp8_kernel<<<1024, 512, 0, stream>>>(xq, wq, bs, out);
}